// Round 2
// baseline (220.546 us; speedup 1.0000x reference)
//
#include <hip/hip_runtime.h>

#define N_NODES 10000
#define N_EDGES 640000
#define D 128

__device__ __forceinline__ void fma4(float4& a, float s, const float4& b) {
    a.x += s * b.x; a.y += s * b.y; a.z += s * b.z; a.w += s * b.w;
}

// h = x @ W  [10000 x 128], all f32. One block = 32 nodes, 8 threads/node.
// W staged in LDS (64 KB). Thread (nl=t>>3, cg=t&7) computes cols
// {4*cg + 32*m + q}, m,q in 0..3 — float4 LDS reads start at bank 4*cg;
// the 8 col-groups span all 32 banks, same-cg lanes broadcast => conflict-free.
__global__ __launch_bounds__(256) void gemm_kernel(
    const float* __restrict__ x, const float* __restrict__ w,
    float* __restrict__ h)
{
    __shared__ float Wf[D * D];  // 64 KB
    const int t = threadIdx.x;
    #pragma unroll
    for (int j = 0; j < 16; ++j) {
        int idx = t + j * 256;                        // 4096 float4 chunks
        *(float4*)&Wf[idx * 4] = *(const float4*)&w[idx * 4];
    }
    __syncthreads();

    const int nl = t >> 3;
    const int cg = t & 7;
    const int n  = blockIdx.x * 32 + nl;
    const int nc = (n < N_NODES) ? n : (N_NODES - 1);  // clamp: avoid OOB reads
    const float* xrow = x + (long)nc * D;

    float4 a0 = {0,0,0,0}, a1 = {0,0,0,0}, a2 = {0,0,0,0}, a3 = {0,0,0,0};
    #pragma unroll 4
    for (int k = 0; k < D; ++k) {
        float a = xrow[k];
        const float* wr = &Wf[k * D + cg * 4];
        float4 w0 = *(const float4*)(wr);
        float4 w1 = *(const float4*)(wr + 32);
        float4 w2 = *(const float4*)(wr + 64);
        float4 w3 = *(const float4*)(wr + 96);
        fma4(a0, a, w0); fma4(a1, a, w1); fma4(a2, a, w2); fma4(a3, a, w3);
    }
    if (n < N_NODES) {
        float* base = h + (long)n * D;
        *(float4*)(base + 4 * cg)      = a0;
        *(float4*)(base + 4 * cg + 32) = a1;
        *(float4*)(base + 4 * cg + 64) = a2;
        *(float4*)(base + 4 * cg + 96) = a3;
    }
}

__global__ __launch_bounds__(256) void hist_kernel(
    const int* __restrict__ row, int* __restrict__ counts)
{
    int e = blockIdx.x * 256 + threadIdx.x;
    if (e < N_EDGES) atomicAdd(&counts[row[e]], 1);
}

// Single-block exclusive scan of 10000 counts -> row_start[10001].
__global__ __launch_bounds__(256) void scan_kernel(
    const int* __restrict__ counts, int* __restrict__ row_start)
{
    __shared__ int part[256];
    const int t = threadIdx.x;
    const int base = t * 40;
    int s = 0;
    for (int i = 0; i < 40; ++i) {
        int idx = base + i;
        if (idx < N_NODES) s += counts[idx];
    }
    part[t] = s;
    __syncthreads();
    for (int off = 1; off < 256; off <<= 1) {
        int v = part[t];
        int u = (t >= off) ? part[t - off] : 0;
        __syncthreads();
        part[t] = v + u;
        __syncthreads();
    }
    int excl = (t == 0) ? 0 : part[t - 1];
    for (int i = 0; i < 40; ++i) {
        int idx = base + i;
        if (idx < N_NODES) {
            row_start[idx] = excl;
            excl += counts[idx];
        }
    }
    if (t == 255) row_start[N_NODES] = part[255];
}

// Bucket edges by row: pairs[pos] = {col, f32_bits(val)}.
__global__ __launch_bounds__(256) void scatter_kernel(
    const int* __restrict__ row, const int* __restrict__ col,
    const float* __restrict__ val, const int* __restrict__ row_start,
    int* __restrict__ cursor, int2* __restrict__ pairs)
{
    int e = blockIdx.x * 256 + threadIdx.x;
    if (e >= N_EDGES) return;
    int r = row[e];
    int pos = row_start[r] + atomicAdd(&cursor[r], 1);
    int2 p;
    p.x = col[e];
    p.y = __float_as_int(val[e]);
    pairs[pos] = p;
}

// One wave per row. Lane l owns cols 2l, 2l+1 (float2 per lane).
// Per edge: one uniform 8B pair load (broadcast) + one coalesced 512B h read.
__global__ __launch_bounds__(256) void spmm_kernel(
    const int2* __restrict__ pairs, const int* __restrict__ row_start,
    const float* __restrict__ h, const float* __restrict__ bias,
    float* __restrict__ out)
{
    const int wave = (int)((blockIdx.x * 256 + threadIdx.x) >> 6);  // = row
    const int lane = threadIdx.x & 63;
    if (wave >= N_NODES) return;
    const int s = row_start[wave];
    const int e = row_start[wave + 1];
    float acc0 = 0.f, acc1 = 0.f;
    #pragma unroll 4
    for (int i = s; i < e; ++i) {
        int2 p = pairs[i];
        float v = __int_as_float(p.y);
        float2 hv = *(const float2*)&h[(long)p.x * D + 2 * lane];
        acc0 += v * hv.x;
        acc1 += v * hv.y;
    }
    float2 o;
    o.x = acc0 + bias[2 * lane];
    o.y = acc1 + bias[2 * lane + 1];
    *(float2*)&out[(long)wave * D + 2 * lane] = o;
}

extern "C" void kernel_launch(void* const* d_in, const int* in_sizes, int n_in,
                              void* d_out, int out_size, void* d_ws, size_t ws_size,
                              hipStream_t stream)
{
    const float* x    = (const float*)d_in[0];
    const float* aval = (const float*)d_in[1];
    const float* w    = (const float*)d_in[2];
    const float* bias = (const float*)d_in[3];
    const int* arow   = (const int*)d_in[4];
    const int* acol   = (const int*)d_in[5];

    char* ws = (char*)d_ws;
    int2*  pairs     = (int2*)(ws);                 // 5,120,000 B (8B-aligned)
    float* h         = (float*)(ws + 5120000);      // 5,120,000 B (16B-aligned)
    int*   counts    = (int*)(ws + 10240000);       //    40,000 B
    int*   cursor    = (int*)(ws + 10280000);       //    40,000 B
    int*   row_start = (int*)(ws + 10320000);       //    40,004 B  (~10.4 MB total)

    hipMemsetAsync(ws + 10240000, 0, 80000, stream);  // counts + cursor

    gemm_kernel<<<313, 256, 0, stream>>>(x, w, h);
    hist_kernel<<<N_EDGES / 256, 256, 0, stream>>>(arow, counts);
    scan_kernel<<<1, 256, 0, stream>>>(counts, row_start);
    scatter_kernel<<<N_EDGES / 256, 256, 0, stream>>>(arow, acol, aval, row_start,
                                                      cursor, pairs);
    spmm_kernel<<<(N_NODES * 64) / 256, 256, 0, stream>>>(pairs, row_start, h,
                                                          bias, (float*)d_out);
}

// Round 3
// 188.416 us; speedup vs baseline: 1.1705x; 1.1705x over previous
//
#include <hip/hip_runtime.h>

#define N_NODES 10000
#define N_EDGES 640000
#define D 128

#define GEMM_BLOCKS 157   // 64 nodes per block
#define HIST_BLOCKS 96
#define N_BANDS 4
#define BAND_ROWS 2500    // N_NODES / N_BANDS

typedef unsigned int uint32;

__device__ __forceinline__ uint32 f2bf_bits(float f) {
    uint32 u = __float_as_uint(f);
    return (u + 0x7FFFu + ((u >> 16) & 1u)) >> 16;   // RNE bf16 bits
}
__device__ __forceinline__ uint32 pack2(float lo, float hi) {
    return f2bf_bits(lo) | (f2bf_bits(hi) << 16);
}
__device__ __forceinline__ void fma4(float4& a, float s, const float4& b) {
    a.x += s * b.x; a.y += s * b.y; a.z += s * b.z; a.w += s * b.w;
}

// Fused: blocks [0,GEMM_BLOCKS) compute h2 = pack_bf16(x @ W); blocks
// [GEMM_BLOCKS, +HIST_BLOCKS) histogram adj_row into counts (fire-and-forget
// atomics overlap gemm VALU work).
// GEMM: 64 nodes/block, thread (nl=t>>3, cg=t&7) computes 2 nodes x 16 cols
// {4cg + 32m + q}. Per 4-k step: 2 float4 x-loads + 16 ds_read_b128 for
// 128 FMAs -> FMA-bound. W float4 reads start at bank 4*cg; 8 col-groups
// span all 32 banks, same-cg lanes broadcast => conflict-free.
__global__ __launch_bounds__(256) void gemm_hist_kernel(
    const float* __restrict__ x, const float* __restrict__ w,
    const int* __restrict__ row,
    uint32* __restrict__ h2, int* __restrict__ counts)
{
    if (blockIdx.x >= GEMM_BLOCKS) {
        const int hb = blockIdx.x - GEMM_BLOCKS;
        const int4* row4 = (const int4*)row;
        const int n4 = N_EDGES / 4;
        for (int i = hb * 256 + threadIdx.x; i < n4; i += HIST_BLOCKS * 256) {
            int4 r = row4[i];
            atomicAdd(&counts[r.x], 1);
            atomicAdd(&counts[r.y], 1);
            atomicAdd(&counts[r.z], 1);
            atomicAdd(&counts[r.w], 1);
        }
        return;
    }

    __shared__ float Wf[D * D];  // 64 KB
    const int t = threadIdx.x;
    #pragma unroll
    for (int j = 0; j < 16; ++j) {
        int idx = t + j * 256;
        *(float4*)&Wf[idx * 4] = *(const float4*)&w[idx * 4];
    }
    __syncthreads();

    const int nl = t >> 3;
    const int cg = t & 7;
    const int n0 = blockIdx.x * 64 + nl * 2;
    const int n1 = n0 + 1;
    const int c0 = (n0 < N_NODES) ? n0 : (N_NODES - 1);
    const int c1 = (n1 < N_NODES) ? n1 : (N_NODES - 1);
    const float* xr0 = x + (long)c0 * D;
    const float* xr1 = x + (long)c1 * D;

    float4 a0 = {0,0,0,0}, a1 = {0,0,0,0}, a2 = {0,0,0,0}, a3 = {0,0,0,0};
    float4 b0 = {0,0,0,0}, b1 = {0,0,0,0}, b2 = {0,0,0,0}, b3 = {0,0,0,0};
    #pragma unroll 4
    for (int k4 = 0; k4 < D / 4; ++k4) {
        float4 xa = *(const float4*)&xr0[k4 * 4];
        float4 xb = *(const float4*)&xr1[k4 * 4];
        #pragma unroll
        for (int j = 0; j < 4; ++j) {
            float av = (j == 0) ? xa.x : (j == 1) ? xa.y : (j == 2) ? xa.z : xa.w;
            float bv = (j == 0) ? xb.x : (j == 1) ? xb.y : (j == 2) ? xb.z : xb.w;
            const float* wr = &Wf[(k4 * 4 + j) * D + cg * 4];
            float4 w0 = *(const float4*)(wr);
            float4 w1 = *(const float4*)(wr + 32);
            float4 w2 = *(const float4*)(wr + 64);
            float4 w3 = *(const float4*)(wr + 96);
            fma4(a0, av, w0); fma4(a1, av, w1); fma4(a2, av, w2); fma4(a3, av, w3);
            fma4(b0, bv, w0); fma4(b1, bv, w1); fma4(b2, bv, w2); fma4(b3, bv, w3);
        }
    }
    // uint j of a row packs cols (2j, 2j+1); this thread's cols 4cg+.. -> uints 2cg+..
    if (n0 < N_NODES) {
        uint32* base = h2 + (long)n0 * 64;
        *(uint2*)(base + 2*cg)      = make_uint2(pack2(a0.x,a0.y), pack2(a0.z,a0.w));
        *(uint2*)(base + 2*cg + 16) = make_uint2(pack2(a1.x,a1.y), pack2(a1.z,a1.w));
        *(uint2*)(base + 2*cg + 32) = make_uint2(pack2(a2.x,a2.y), pack2(a2.z,a2.w));
        *(uint2*)(base + 2*cg + 48) = make_uint2(pack2(a3.x,a3.y), pack2(a3.z,a3.w));
    }
    if (n1 < N_NODES) {
        uint32* base = h2 + (long)n1 * 64;
        *(uint2*)(base + 2*cg)      = make_uint2(pack2(b0.x,b0.y), pack2(b0.z,b0.w));
        *(uint2*)(base + 2*cg + 16) = make_uint2(pack2(b1.x,b1.y), pack2(b1.z,b1.w));
        *(uint2*)(base + 2*cg + 32) = make_uint2(pack2(b2.x,b2.y), pack2(b2.z,b2.w));
        *(uint2*)(base + 2*cg + 48) = make_uint2(pack2(b3.x,b3.y), pack2(b3.z,b3.w));
    }
}

// Single-block exclusive scan of counts[10000] -> row_start[10001] AND
// cursor[10000] (working copy for the scatter's atomics).
__global__ __launch_bounds__(256) void scan_kernel(
    const int* __restrict__ counts, int* __restrict__ row_start,
    int* __restrict__ cursor)
{
    __shared__ int part[256];
    const int t = threadIdx.x;
    int4 v[10];
    int s = 0;
    #pragma unroll
    for (int i = 0; i < 10; ++i) {
        int idx4 = t * 10 + i;
        if (idx4 < N_NODES / 4) {
            v[i] = ((const int4*)counts)[idx4];
            s += v[i].x + v[i].y + v[i].z + v[i].w;
        } else {
            v[i] = make_int4(0, 0, 0, 0);
        }
    }
    part[t] = s;
    __syncthreads();
    for (int off = 1; off < 256; off <<= 1) {
        int a = part[t];
        int u = (t >= off) ? part[t - off] : 0;
        __syncthreads();
        part[t] = a + u;
        __syncthreads();
    }
    int excl = (t == 0) ? 0 : part[t - 1];
    #pragma unroll
    for (int i = 0; i < 10; ++i) {
        int idx = t * 40 + i * 4;
        if (idx < N_NODES) {
            row_start[idx]   = excl; cursor[idx]   = excl; excl += v[i].x;
            row_start[idx+1] = excl; cursor[idx+1] = excl; excl += v[i].y;
            row_start[idx+2] = excl; cursor[idx+2] = excl; excl += v[i].z;
            row_start[idx+3] = excl; cursor[idx+3] = excl; excl += v[i].w;
        }
    }
    if (t == 255) row_start[N_NODES] = part[255];
}

// Banded counting scatter: 4 passes over the edge list; band b only places
// rows [b*2500,(b+1)*2500). Active write window = 640 KB (L2-resident) and
// 4B records double stores-per-line => L2 write merging instead of thrash.
// Record = col(u16) | bf16(val)<<16.
__global__ __launch_bounds__(256) void scatter_kernel(
    const int* __restrict__ row, const int* __restrict__ col,
    const float* __restrict__ val, int* __restrict__ cursor,
    uint32* __restrict__ pairs)
{
    const int stride = gridDim.x * 256;
    const int tid = blockIdx.x * 256 + threadIdx.x;
    const int4* row4 = (const int4*)row;
    for (int band = 0; band < N_BANDS; ++band) {
        const int lo = band * BAND_ROWS;
        const int hi = lo + BAND_ROWS;
        for (int i4 = tid; i4 < N_EDGES / 4; i4 += stride) {
            int4 r4 = row4[i4];
            const int e = i4 * 4;
            #pragma unroll
            for (int j = 0; j < 4; ++j) {
                int r = (j == 0) ? r4.x : (j == 1) ? r4.y : (j == 2) ? r4.z : r4.w;
                if (r >= lo && r < hi) {
                    int pos = atomicAdd(&cursor[r], 1);
                    uint32 c = (uint32)col[e + j];
                    pairs[pos] = c | (f2bf_bits(val[e + j]) << 16);
                }
            }
        }
    }
}

// One wave per row; lane l owns cols (2l, 2l+1) via one packed-bf16x2 uint.
// Per edge: one wave-uniform 4B record load + one coalesced 256B h2 gather.
__global__ __launch_bounds__(256) void spmm_kernel(
    const uint32* __restrict__ pairs, const int* __restrict__ row_start,
    const uint32* __restrict__ h2, const float* __restrict__ bias,
    float* __restrict__ out)
{
    const int r    = (int)((blockIdx.x * 256 + threadIdx.x) >> 6);
    const int lane = threadIdx.x & 63;
    if (r >= N_NODES) return;
    const int s = row_start[r];
    const int e = row_start[r + 1];
    float acc0 = 0.f, acc1 = 0.f;
    #pragma unroll 4
    for (int i = s; i < e; ++i) {
        uint32 rec = pairs[i];                            // wave-uniform
        float v  = __uint_as_float(rec & 0xFFFF0000u);    // bf16 val
        uint32 hv = h2[(long)(rec & 0xFFFFu) * 64 + lane];
        acc0 += v * __uint_as_float(hv << 16);            // col 2*lane
        acc1 += v * __uint_as_float(hv & 0xFFFF0000u);    // col 2*lane+1
    }
    float2 o;
    o.x = acc0 + bias[2 * lane];
    o.y = acc1 + bias[2 * lane + 1];
    *(float2*)&out[(long)r * D + 2 * lane] = o;
}

extern "C" void kernel_launch(void* const* d_in, const int* in_sizes, int n_in,
                              void* d_out, int out_size, void* d_ws, size_t ws_size,
                              hipStream_t stream)
{
    const float* x    = (const float*)d_in[0];
    const float* aval = (const float*)d_in[1];
    const float* w    = (const float*)d_in[2];
    const float* bias = (const float*)d_in[3];
    const int* arow   = (const int*)d_in[4];
    const int* acol   = (const int*)d_in[5];

    char* ws = (char*)d_ws;
    uint32* pairs    = (uint32*)(ws);             // 2,560,000 B
    uint32* h2       = (uint32*)(ws + 2560000);   // 2,560,000 B
    int*    counts   = (int*)(ws + 5120000);      //    40,000 B
    int*    row_start= (int*)(ws + 5160000);      //    40,004 B
    int*    cursor   = (int*)(ws + 5200016);      //    40,000 B

    hipMemsetAsync(counts, 0, 40000, stream);

    gemm_hist_kernel<<<GEMM_BLOCKS + HIST_BLOCKS, 256, 0, stream>>>(
        x, w, arow, h2, counts);
    scan_kernel<<<1, 256, 0, stream>>>(counts, row_start, cursor);
    scatter_kernel<<<512, 256, 0, stream>>>(arow, acol, aval, cursor, pairs);
    spmm_kernel<<<(N_NODES * 64) / 256, 256, 0, stream>>>(
        pairs, row_start, h2, bias, (float*)d_out);
}